// Round 14
// baseline (123.318 us; speedup 1.0000x reference)
//
#include <hip/hip_runtime.h>
#include <hip/hip_bf16.h>

#define S_LEN 4096
#define DMODEL 512
#define NHEAD 8
#define HDIM 64

typedef __bf16 bf16x8 __attribute__((ext_vector_type(8)));
typedef __bf16 bf16x4 __attribute__((ext_vector_type(4)));
typedef short s16x4 __attribute__((ext_vector_type(4)));
typedef float f32x4 __attribute__((ext_vector_type(4)));

#define S2EXP 0.18033688011112042f   // 0.125 * log2(e), folded into Q projection

__device__ __forceinline__ void gload_lds16(const void* g, void* l) {
    __builtin_amdgcn_global_load_lds((const __attribute__((address_space(1))) void*)g,
                                     (__attribute__((address_space(3))) void*)l, 16, 0, 0);
}
__device__ __forceinline__ void gload_lds4(const void* g, void* l) {
    __builtin_amdgcn_global_load_lds((const __attribute__((address_space(1))) void*)g,
                                     (__attribute__((address_space(3))) void*)l, 4, 0, 0);
}
__device__ __forceinline__ f32x4 mfma16(bf16x4 a, bf16x4 b, f32x4 c) {
    return __builtin_amdgcn_mfma_f32_16x16x16bf16_1k(__builtin_bit_cast(s16x4, a),
                                                     __builtin_bit_cast(s16x4, b), c, 0, 0, 0);
}

// ---------------- fused projections: blocks 0-511 q+k, 512-1023 v(+transpose) ----------------
__global__ __launch_bounds__(256) void proj_all_kernel(const float* __restrict__ xq,
                                                       const float* __restrict__ xk,
                                                       const float* __restrict__ xv,
                                                       const float* __restrict__ Wq,
                                                       const float* __restrict__ bq,
                                                       const float* __restrict__ Wk,
                                                       const float* __restrict__ bk,
                                                       const float* __restrict__ Wv,
                                                       const float* __restrict__ bv,
                                                       __bf16* __restrict__ yq,
                                                       __bf16* __restrict__ yk,
                                                       __bf16* __restrict__ vt) {
    __shared__ float T[64][65];
    int bid = blockIdx.x;
    int t = threadIdx.x, wave = t >> 6, lane = t & 63, lg = lane >> 4, lc = lane & 15;
    if (bid < 512) {
        int r0 = bid * 64 + wave * 16;
        const float* xrq = xq + (size_t)(r0 + lc) * 64 + lg * 8;
        const float* xrk = xk + (size_t)(r0 + lc) * 64 + lg * 8;
        bf16x8 aq[2], ak[2];
#pragma unroll
        for (int c = 0; c < 2; ++c) {
            f32x4 u0 = *(const f32x4*)(xrq + c * 32);
            f32x4 u1 = *(const f32x4*)(xrq + c * 32 + 4);
            f32x4 v0 = *(const f32x4*)(xrk + c * 32);
            f32x4 v1 = *(const f32x4*)(xrk + c * 32 + 4);
            bf16x8 a, b;
#pragma unroll
            for (int j = 0; j < 4; ++j) {
                a[j] = (__bf16)u0[j]; a[4 + j] = (__bf16)u1[j];
                b[j] = (__bf16)v0[j]; b[4 + j] = (__bf16)v1[j];
            }
            aq[c] = a; ak[c] = b;
        }
#pragma unroll
        for (int nt = 0; nt < 4; ++nt) {
            const float* wq = Wq + (size_t)(nt * 16 + lc) * 64 + lg * 8;
            const float* wk = Wk + (size_t)(nt * 16 + lc) * 64 + lg * 8;
            f32x4 cq = {0, 0, 0, 0}, ck = {0, 0, 0, 0};
#pragma unroll
            for (int c = 0; c < 2; ++c) {
                f32x4 u0 = *(const f32x4*)(wq + c * 32);
                f32x4 u1 = *(const f32x4*)(wq + c * 32 + 4);
                f32x4 v0 = *(const f32x4*)(wk + c * 32);
                f32x4 v1 = *(const f32x4*)(wk + c * 32 + 4);
                bf16x8 bw, bw2;
#pragma unroll
                for (int j = 0; j < 4; ++j) {
                    bw[j] = (__bf16)u0[j]; bw[4 + j] = (__bf16)u1[j];
                    bw2[j] = (__bf16)v0[j]; bw2[4 + j] = (__bf16)v1[j];
                }
                cq = __builtin_amdgcn_mfma_f32_16x16x32_bf16(aq[c], bw, cq, 0, 0, 0);
                ck = __builtin_amdgcn_mfma_f32_16x16x32_bf16(ak[c], bw2, ck, 0, 0, 0);
            }
            float bqv = bq[nt * 16 + lc], bkv = bk[nt * 16 + lc];
#pragma unroll
            for (int r = 0; r < 4; ++r) {
                yq[(size_t)(r0 + lg * 4 + r) * 64 + nt * 16 + lc] = (__bf16)((cq[r] + bqv) * S2EXP);
                yk[(size_t)(r0 + lg * 4 + r) * 64 + nt * 16 + lc] = (__bf16)(ck[r] + bkv);
            }
        }
    } else {
        int vb = bid - 512;
        int h = vb & 7, s0 = (vb >> 3) * 64;
        const float* xr = xv + ((size_t)(s0 + wave * 16 + lc) * 8 + h) * 64 + lg * 8;
        bf16x8 av[2];
#pragma unroll
        for (int c = 0; c < 2; ++c) {
            f32x4 u0 = *(const f32x4*)(xr + c * 32);
            f32x4 u1 = *(const f32x4*)(xr + c * 32 + 4);
            bf16x8 a;
#pragma unroll
            for (int j = 0; j < 4; ++j) { a[j] = (__bf16)u0[j]; a[4 + j] = (__bf16)u1[j]; }
            av[c] = a;
        }
#pragma unroll
        for (int nt = 0; nt < 4; ++nt) {
            const float* wv = Wv + (size_t)(nt * 16 + lc) * 64 + lg * 8;
            f32x4 cv = {0, 0, 0, 0};
#pragma unroll
            for (int c = 0; c < 2; ++c) {
                f32x4 u0 = *(const f32x4*)(wv + c * 32);
                f32x4 u1 = *(const f32x4*)(wv + c * 32 + 4);
                bf16x8 bw;
#pragma unroll
                for (int j = 0; j < 4; ++j) { bw[j] = (__bf16)u0[j]; bw[4 + j] = (__bf16)u1[j]; }
                cv = __builtin_amdgcn_mfma_f32_16x16x32_bf16(av[c], bw, cv, 0, 0, 0);
            }
            float bvv = bv[nt * 16 + lc];
#pragma unroll
            for (int r = 0; r < 4; ++r) T[wave * 16 + lg * 4 + r][nt * 16 + lc] = cv[r] + bvv;
        }
        __syncthreads();
        int d = t >> 2, qr = t & 3;
        bf16x8 w0, w1;
#pragma unroll
        for (int i = 0; i < 8; ++i) {
            w0[i] = (__bf16)T[qr * 16 + i][d];
            w1[i] = (__bf16)T[qr * 16 + 8 + i][d];
        }
        __bf16* dst = vt + ((size_t)h * 64 + d) * 4096 + s0 + qr * 16;
        *(bf16x8*)(dst) = w0;
        *(bf16x8*)(dst + 8) = w1;
    }
}

// ---------------- prep: blocks 0-2047 mask packing, 2048-2079 Wfc f32->bf16 ----------------
__global__ __launch_bounds__(256) void prep_kernel(const int* __restrict__ mask,
                                                   unsigned int* __restrict__ pack,
                                                   const float* __restrict__ Wfc,
                                                   __bf16* __restrict__ wfc_bf) {
    int bid = blockIdx.x;
    int t = threadIdx.x;
    if (bid < 2048) {
        int lane = t & 63;
        int wid = bid * 4 + (t >> 6);
#pragma unroll 4
        for (int it = 0; it < 32; ++it) {
            int gw = wid * 32 + it;
            int qi = gw >> 6, seg = gw & 63;
            unsigned long long bits = __ballot(mask[(size_t)qi * 4096 + seg * 64 + lane] != 0);
            if (lane == 0)
                *(unsigned long long*)(&pack[(size_t)qi * 128 + seg * 2]) = bits;
        }
    } else {
        int b = bid - 2048;
        const f32x4* s4 = (const f32x4*)Wfc;
#pragma unroll
        for (int i = 0; i < 8; ++i) {
            int idx = (b * 8 + i) * 256 + t;     // f32x4 index, 65536 total
            f32x4 v = s4[idx];
            bf16x4 o;
#pragma unroll
            for (int j = 0; j < 4; ++j) o[j] = (__bf16)v[j];
            *(bf16x4*)(wfc_bf + (size_t)idx * 4) = o;
        }
    }
}

// ---------------- flash attention: 32 q/wave, P kept in registers (K=16 PV), 4-buf vmcnt ring ----------------
// block: h = bid&7 (head -> XCD), qtb = (bid>>3)&31 (128 q-rows), sp = bid>>8
// QK^T swapped (mfma(K,Q)) leaves lane lc+16*lg, reg r with P[k=kc*16+lg*4+r][q=lc] — exactly the
// B-fragment of mfma_f32_16x16x16_bf16. PV = mfma(A = V^T 8B fragment from vt, B = P) -> D[d][q],
// so P never touches LDS. V A-fragments are shared across both q-tiles.
__global__ __launch_bounds__(256, 4) void attn_kernel(const __bf16* __restrict__ qb,
                                                      const __bf16* __restrict__ kb,
                                                      const __bf16* __restrict__ vt,
                                                      const unsigned int* __restrict__ mp,
                                                      int split_steps,
                                                      float* __restrict__ opart,
                                                      float* __restrict__ stats,
                                                      __bf16* __restrict__ ao) {
    int bid = blockIdx.x;
    int h = bid & 7, qtb = (bid >> 3) & 31, sp = bid >> 8;
    int kv0 = sp * split_steps * 32;
    int nsteps = split_steps;            // 32 / 64 / 128 — always divisible by 4
    int t = threadIdx.x, wave = t >> 6, lane = t & 63, lg = lane >> 4, lc = lane & 15;
    int q0 = qtb * 128 + wave * 32;

    __shared__ __bf16 Kt[4][32 * 64];        // 16KB: k-rows, 128B, XOR swz ((row&7)<<4)
    __shared__ __bf16 Vt[4][64 * 32];        // 16KB: d-rows, 64B, 16B-chunk rotation swz
    __shared__ unsigned int Mld[4][128];     // 2KB: mask word per q-row per buffered tile

    int srK = lane >> 3;
    int cgK = (lane & 7) ^ srK;                      // inverse XOR swizzle (K)
    int cgV = ((lane & 3) - ((lane >> 3) & 3)) & 3;  // inverse rotation (V): phys=(log+(row>>1))&3
    int srV = lane >> 2;

    const __bf16* qr0 = qb + ((size_t)(q0 + lc) * 8 + h) * 64 + lg * 8;
    const __bf16* qr1 = qb + ((size_t)(q0 + 16 + lc) * 8 + h) * 64 + lg * 8;
    bf16x8 qf00 = *(const bf16x8*)(qr0);
    bf16x8 qf01 = *(const bf16x8*)(qr0 + 32);
    bf16x8 qf10 = *(const bf16x8*)(qr1);
    bf16x8 qf11 = *(const bf16x8*)(qr1 + 32);

    bf16x4 onesA;
#pragma unroll
    for (int j = 0; j < 4; ++j) onesA[j] = (__bf16)1.0f;

    f32x4 o00 = {0,0,0,0}, o01 = {0,0,0,0}, o02 = {0,0,0,0}, o03 = {0,0,0,0};
    f32x4 o10 = {0,0,0,0}, o11 = {0,0,0,0}, o12 = {0,0,0,0}, o13 = {0,0,0,0};
    f32x4 lac0 = {0,0,0,0}, lac1 = {0,0,0,0};

    const __bf16* vbase = vt + (size_t)h * 64 * 4096;
    const unsigned int* mbase = mp + (size_t)(qtb * 128 + wave * 64 + lane) * 128 + (kv0 >> 5);

    int lg4 = lg * 4;
    // loop-invariant V read offsets (within a row): phys16 = (kc*2 + (lg>>1) + (row>>1)) & 3,
    // and (row>>1)&3 = (lc>>1)&3 since row = dt*16+lc.
    int vch0 = ((((lg >> 1) + (lc >> 1)) & 3) * 16) + (lg & 1) * 8;        // kc=0
    int vch1 = (((2 + (lg >> 1) + (lc >> 1)) & 3) * 16) + (lg & 1) * 8;    // kc=1

#define STAGE(tt, B)                                                                          \
    {                                                                                         \
        if (wave < 2) gload_lds4(mbase + (tt), &Mld[B][wave * 64]);                           \
        gload_lds16(kb + (size_t)(kv0 + (tt) * 32 + wave * 8 + srK) * 512 + h * 64 + cgK * 8, \
                    &Kt[B][wave * 512]);                                                      \
        gload_lds16(vbase + (size_t)(wave * 16 + srV) * 4096 + kv0 + (tt) * 32 + cgV * 8,     \
                    &Vt[B][wave * 512]);                                                      \
    }

    // ---- prologue: stage tiles 0,1; full drain once ----
    STAGE(0, 0)
    STAGE(1, 1)
    asm volatile("s_waitcnt vmcnt(0)" ::: "memory");
    __builtin_amdgcn_s_barrier();

#define ATTN_STEP(s, C, G)                                                                    \
    {                                                                                         \
        STAGE(min((s) + 2, nsteps - 1), G)                                                    \
        asm volatile("s_waitcnt vmcnt(4)" ::: "memory");                                      \
        __builtin_amdgcn_s_barrier();                                                         \
        unsigned int mw0 = Mld[C][wave * 32 + lc] >> lg4;                                     \
        unsigned int mw1 = Mld[C][wave * 32 + 16 + lc] >> lg4;                                \
        const char* Kb = (const char*)&Kt[C][0];                                              \
        f32x4 s00 = {0,0,0,0}, s01 = {0,0,0,0}, s10 = {0,0,0,0}, s11 = {0,0,0,0};             \
        {                                                                                     \
            int row = lc, sw = (row & 7) << 4;                                                \
            bf16x8 ka = *(const bf16x8*)(Kb + ((row * 128 + lg * 16) ^ sw));                  \
            bf16x8 kc_ = *(const bf16x8*)(Kb + ((row * 128 + 64 + lg * 16) ^ sw));            \
            s00 = __builtin_amdgcn_mfma_f32_16x16x32_bf16(ka, qf00, s00, 0, 0, 0);            \
            s00 = __builtin_amdgcn_mfma_f32_16x16x32_bf16(kc_, qf01, s00, 0, 0, 0);           \
            s01 = __builtin_amdgcn_mfma_f32_16x16x32_bf16(ka, qf10, s01, 0, 0, 0);            \
            s01 = __builtin_amdgcn_mfma_f32_16x16x32_bf16(kc_, qf11, s01, 0, 0, 0);           \
        }                                                                                     \
        {                                                                                     \
            int row = 16 + lc, sw = (row & 7) << 4;                                           \
            bf16x8 ka = *(const bf16x8*)(Kb + ((row * 128 + lg * 16) ^ sw));                  \
            bf16x8 kc_ = *(const bf16x8*)(Kb + ((row * 128 + 64 + lg * 16) ^ sw));            \
            s10 = __builtin_amdgcn_mfma_f32_16x16x32_bf16(ka, qf00, s10, 0, 0, 0);            \
            s10 = __builtin_amdgcn_mfma_f32_16x16x32_bf16(kc_, qf01, s10, 0, 0, 0);           \
            s11 = __builtin_amdgcn_mfma_f32_16x16x32_bf16(ka, qf10, s11, 0, 0, 0);            \
            s11 = __builtin_amdgcn_mfma_f32_16x16x32_bf16(kc_, qf11, s11, 0, 0, 0);           \
        }                                                                                     \
        bf16x4 pk00, pk10, pk01, pk11;   /* pk[kc][qt] */                                     \
        _Pragma("unroll")                                                                     \
        for (int r = 0; r < 4; ++r) {                                                         \
            float pa = __builtin_amdgcn_exp2f(s00[r]);                                        \
            pk00[r] = (__bf16)__int_as_float(__float_as_int(pa) &                             \
                                             __builtin_amdgcn_sbfe((int)mw0, r, 1));          \
            float pc = __builtin_amdgcn_exp2f(s10[r]);                                        \
            pk10[r] = (__bf16)__int_as_float(__float_as_int(pc) &                             \
                                             __builtin_amdgcn_sbfe((int)mw0, 16 + r, 1));     \
            float pd = __builtin_amdgcn_exp2f(s01[r]);                                        \
            pk01[r] = (__bf16)__int_as_float(__float_as_int(pd) &                             \
                                             __builtin_amdgcn_sbfe((int)mw1, r, 1));          \
            float pe = __builtin_amdgcn_exp2f(s11[r]);                                        \
            pk11[r] = (__bf16)__int_as_float(__float_as_int(pe) &                             \
                                             __builtin_amdgcn_sbfe((int)mw1, 16 + r, 1));     \
        }                                                                                     \
        lac0 = mfma16(onesA, pk00, lac0);                                                     \
        lac0 = mfma16(onesA, pk10, lac0);                                                     \
        lac1 = mfma16(onesA, pk01, lac1);                                                     \
        lac1 = mfma16(onesA, pk11, lac1);                                                     \
        const char* Vb = (const char*)&Vt[C][0];                                              \
        {                                                                                     \
            int rb = (0 * 16 + lc) * 64;                                                      \
            bf16x4 v0 = *(const bf16x4*)(Vb + rb + vch0);                                     \
            bf16x4 v1 = *(const bf16x4*)(Vb + rb + vch1);                                     \
            o00 = mfma16(v0, pk00, o00); o00 = mfma16(v1, pk10, o00);                         \
            o10 = mfma16(v0, pk01, o10); o10 = mfma16(v1, pk11, o10);                         \
        }                                                                                     \
        {                                                                                     \
            int rb = (1 * 16 + lc) * 64;                                                      \
            bf16x4 v0 = *(const bf16x4*)(Vb + rb + vch0);                                     \
            bf16x4 v1 = *(const bf16x4*)(Vb + rb + vch1);                                     \
            o01 = mfma16(v0, pk00, o01); o01 = mfma16(v1, pk10, o01);                         \
            o11 = mfma16(v0, pk01, o11); o11 = mfma16(v1, pk11, o11);                         \
        }                                                                                     \
        {                                                                                     \
            int rb = (2 * 16 + lc) * 64;                                                      \
            bf16x4 v0 = *(const bf16x4*)(Vb + rb + vch0);                                     \
            bf16x4 v1 = *(const bf16x4*)(Vb + rb + vch1);                                     \
            o02 = mfma16(v0, pk00, o02); o02 = mfma16(v1, pk10, o02);                         \
            o12 = mfma16(v0, pk01, o12); o12 = mfma16(v1, pk11, o12);                         \
        }                                                                                     \
        {                                                                                     \
            int rb = (3 * 16 + lc) * 64;                                                      \
            bf16x4 v0 = *(const bf16x4*)(Vb + rb + vch0);                                     \
            bf16x4 v1 = *(const bf16x4*)(Vb + rb + vch1);                                     \
            o03 = mfma16(v0, pk00, o03); o03 = mfma16(v1, pk10, o03);                         \
            o13 = mfma16(v0, pk01, o13); o13 = mfma16(v1, pk11, o13);                         \
        }                                                                                     \
    }

    for (int s = 0; s < nsteps; s += 4) {
        ATTN_STEP(s + 0, 0, 2)
        ATTN_STEP(s + 1, 1, 3)
        ATTN_STEP(s + 2, 2, 0)
        ATTN_STEP(s + 3, 3, 1)
    }
#undef ATTN_STEP
#undef STAGE

    // ---- epilogue: lane lc+16*lg holds O[q=lc(+16 for qt1)][d = dt*16 + lg*4 + r] ----
    if (opart) {
        if (lg == 0) {
            stats[(size_t)sp * 32768 + (size_t)(q0 + lc) * 8 + h]      = lac0[0];
            stats[(size_t)sp * 32768 + (size_t)(q0 + 16 + lc) * 8 + h] = lac1[0];
        }
        size_t rh0 = (size_t)sp * 32768 + (size_t)(q0 + lc) * 8 + h;
        size_t rh1 = (size_t)sp * 32768 + (size_t)(q0 + 16 + lc) * 8 + h;
        float* d0 = opart + rh0 * 64 + lg4;
        float* d1 = opart + rh1 * 64 + lg4;
        *(f32x4*)(d0 + 0)  = o00; *(f32x4*)(d0 + 16) = o01;
        *(f32x4*)(d0 + 32) = o02; *(f32x4*)(d0 + 48) = o03;
        *(f32x4*)(d1 + 0)  = o10; *(f32x4*)(d1 + 16) = o11;
        *(f32x4*)(d1 + 32) = o12; *(f32x4*)(d1 + 48) = o13;
    } else {
        float inv0 = 1.0f / lac0[0];
        float inv1 = 1.0f / lac1[0];
        __bf16* d0 = ao + (size_t)(q0 + lc) * 512 + h * 64 + lg4;
        __bf16* d1 = ao + (size_t)(q0 + 16 + lc) * 512 + h * 64 + lg4;
        bf16x4 w;
#pragma unroll
        for (int r = 0; r < 4; ++r) w[r] = (__bf16)(o00[r] * inv0);
        *(bf16x4*)(d0 + 0) = w;
#pragma unroll
        for (int r = 0; r < 4; ++r) w[r] = (__bf16)(o01[r] * inv0);
        *(bf16x4*)(d0 + 16) = w;
#pragma unroll
        for (int r = 0; r < 4; ++r) w[r] = (__bf16)(o02[r] * inv0);
        *(bf16x4*)(d0 + 32) = w;
#pragma unroll
        for (int r = 0; r < 4; ++r) w[r] = (__bf16)(o03[r] * inv0);
        *(bf16x4*)(d0 + 48) = w;
#pragma unroll
        for (int r = 0; r < 4; ++r) w[r] = (__bf16)(o10[r] * inv1);
        *(bf16x4*)(d1 + 0) = w;
#pragma unroll
        for (int r = 0; r < 4; ++r) w[r] = (__bf16)(o11[r] * inv1);
        *(bf16x4*)(d1 + 16) = w;
#pragma unroll
        for (int r = 0; r < 4; ++r) w[r] = (__bf16)(o12[r] * inv1);
        *(bf16x4*)(d1 + 32) = w;
#pragma unroll
        for (int r = 0; r < 4; ++r) w[r] = (__bf16)(o13[r] * inv1);
        *(bf16x4*)(d1 + 48) = w;
    }
}

// ---------------- split-KV combine (no-max softmax: plain sums) ----------------
__global__ __launch_bounds__(256) void combine_kernel(const float* __restrict__ opart,
                                                      const float* __restrict__ stats,
                                                      __bf16* __restrict__ ao, int nsplit) {
    int t = threadIdx.x, lane = t & 63, w = t >> 6;
    int rh = blockIdx.x * 4 + w;     // row*8 + h
    float L = 0.f, acc = 0.f;
#pragma unroll 4
    for (int sp = 0; sp < nsplit; ++sp) {
        L += stats[(size_t)sp * 32768 + rh];
        acc += opart[((size_t)sp * 32768 + rh) * 64 + lane];
    }
    int row = rh >> 3, h = rh & 7;
    ao[(size_t)row * 512 + h * 64 + lane] = (__bf16)(acc / L);
}

// ---------------- final FC: out[s][n] = sum_k ao[s][k] * Wfc[n][k] + bfc[n] ----------------
__global__ __launch_bounds__(256) void fc_kernel(const __bf16* __restrict__ ao,
                                                 const __bf16* __restrict__ Wb,
                                                 const float* __restrict__ bfc,
                                                 float* __restrict__ out) {
    int bid = blockIdx.x;
    int stile = bid >> 3, nt = bid & 7;
    int t = threadIdx.x, wave = t >> 6, lane = t & 63, lg = lane >> 4, lc = lane & 15;
    int s0 = stile * 64 + wave * 16;
    int n0 = nt * 64;
    f32x4 c0 = {0,0,0,0}, c1 = {0,0,0,0}, c2 = {0,0,0,0}, c3 = {0,0,0,0};
    for (int k0 = 0; k0 < 512; k0 += 32) {
        bf16x8 af = *(const bf16x8*)(ao + (size_t)(s0 + lc) * 512 + k0 + lg * 8);
        const __bf16* wb = Wb + k0 + lg * 8;
        c0 = __builtin_amdgcn_mfma_f32_16x16x32_bf16(af, *(const bf16x8*)(wb + (size_t)(n0 + 0 * 16 + lc) * 512), c0, 0, 0, 0);
        c1 = __builtin_amdgcn_mfma_f32_16x16x32_bf16(af, *(const bf16x8*)(wb + (size_t)(n0 + 1 * 16 + lc) * 512), c1, 0, 0, 0);
        c2 = __builtin_amdgcn_mfma_f32_16x16x32_bf16(af, *(const bf16x8*)(wb + (size_t)(n0 + 2 * 16 + lc) * 512), c2, 0, 0, 0);
        c3 = __builtin_amdgcn_mfma_f32_16x16x32_bf16(af, *(const bf16x8*)(wb + (size_t)(n0 + 3 * 16 + lc) * 512), c3, 0, 0, 0);
    }
#pragma unroll
    for (int r = 0; r < 4; ++r) {
        int row = s0 + lg * 4 + r;
        float* dst = out + (size_t)row * 512 + n0;
        dst[0 * 16 + lc] = c0[r] + bfc[n0 + 0 * 16 + lc];
        dst[1 * 16 + lc] = c1[r] + bfc[n0 + 1 * 16 + lc];
        dst[2 * 16 + lc] = c2[r] + bfc[n0 + 2 * 16 + lc];
        dst[3 * 16 + lc] = c3[r] + bfc[n0 + 3 * 16 + lc];
    }
}

extern "C" void kernel_launch(void* const* d_in, const int* in_sizes, int n_in,
                              void* d_out, int out_size, void* d_ws, size_t ws_size,
                              hipStream_t stream) {
    const float* query = (const float*)d_in[0];
    const float* key   = (const float*)d_in[1];
    const float* value = (const float*)d_in[2];
    const int*   mask  = (const int*)d_in[3];
    const float* Wq  = (const float*)d_in[4];
    const float* bq  = (const float*)d_in[5];
    const float* Wk  = (const float*)d_in[6];
    const float* bk  = (const float*)d_in[7];
    const float* Wv  = (const float*)d_in[8];
    const float* bv  = (const float*)d_in[9];
    const float* Wfc = (const float*)d_in[10];
    const float* bfc = (const float*)d_in[11];

    char* ws = (char*)d_ws;
    const size_t MB = 1024 * 1024;
    __bf16* q_bf   = (__bf16*)(ws + 0 * MB);      // 4 MB  [S*H][64]
    __bf16* k_bf   = (__bf16*)(ws + 4 * MB);      // 4 MB  [S*H][64]
    __bf16* vt     = (__bf16*)(ws + 8 * MB);      // 4 MB  [H][64][S]
    __bf16* ao     = (__bf16*)(ws + 12 * MB);     // 4 MB  [S][512]
    __bf16* wfc_bf = (__bf16*)(ws + 16 * MB);     // 0.5 MB
    unsigned int* mpack = (unsigned int*)(ws + 17 * MB);  // 2 MB [S][128]
    const size_t base = 19 * MB;
    int nsplit = 1, split_steps = 128;
    if (ws_size >= base + 4 * (8 * MB) + 4 * 131072)      { nsplit = 4; split_steps = 32; }
    else if (ws_size >= base + 2 * (8 * MB) + 2 * 131072) { nsplit = 2; split_steps = 64; }
    float* opart = (float*)(ws + base);
    float* stats = (float*)(ws + base + (size_t)nsplit * 8 * MB);

    proj_all_kernel<<<1024, 256, 0, stream>>>(query, key, value, Wq, bq, Wk, bk, Wv, bv,
                                              q_bf, k_bf, vt);
    prep_kernel<<<2080, 256, 0, stream>>>(mask, mpack, Wfc, wfc_bf);
    if (nsplit > 1) {
        attn_kernel<<<256 * nsplit, 256, 0, stream>>>(q_bf, k_bf, vt, mpack,
                                                      split_steps, opart, stats, ao);
        combine_kernel<<<8192, 256, 0, stream>>>(opart, stats, ao, nsplit);
    } else {
        attn_kernel<<<256, 256, 0, stream>>>(q_bf, k_bf, vt, mpack,
                                             128, nullptr, nullptr, ao);
    }
    fc_kernel<<<512, 256, 0, stream>>>(ao, wfc_bf, bfc, (float*)d_out);
}

// Round 15
// 119.996 us; speedup vs baseline: 1.0277x; 1.0277x over previous
//
#include <hip/hip_runtime.h>
#include <hip/hip_bf16.h>

#define S_LEN 4096
#define DMODEL 512
#define NHEAD 8
#define HDIM 64

typedef __bf16 bf16x8 __attribute__((ext_vector_type(8)));
typedef __bf16 bf16x4 __attribute__((ext_vector_type(4)));
typedef short s16x4 __attribute__((ext_vector_type(4)));
typedef float f32x4 __attribute__((ext_vector_type(4)));

#define S2EXP 0.18033688011112042f   // 0.125 * log2(e), folded into Q projection

__device__ __forceinline__ void gload_lds16(const void* g, void* l) {
    __builtin_amdgcn_global_load_lds((const __attribute__((address_space(1))) void*)g,
                                     (__attribute__((address_space(3))) void*)l, 16, 0, 0);
}
__device__ __forceinline__ void gload_lds4(const void* g, void* l) {
    __builtin_amdgcn_global_load_lds((const __attribute__((address_space(1))) void*)g,
                                     (__attribute__((address_space(3))) void*)l, 4, 0, 0);
}
__device__ __forceinline__ f32x4 mfma16(bf16x4 a, bf16x4 b, f32x4 c) {
    return __builtin_amdgcn_mfma_f32_16x16x16bf16_1k(__builtin_bit_cast(s16x4, a),
                                                     __builtin_bit_cast(s16x4, b), c, 0, 0, 0);
}

// ---------------- fused projections: blocks 0-511 q+k, 512-1023 v(+transpose) ----------------
__global__ __launch_bounds__(256) void proj_all_kernel(const float* __restrict__ xq,
                                                       const float* __restrict__ xk,
                                                       const float* __restrict__ xv,
                                                       const float* __restrict__ Wq,
                                                       const float* __restrict__ bq,
                                                       const float* __restrict__ Wk,
                                                       const float* __restrict__ bk,
                                                       const float* __restrict__ Wv,
                                                       const float* __restrict__ bv,
                                                       __bf16* __restrict__ yq,
                                                       __bf16* __restrict__ yk,
                                                       __bf16* __restrict__ vt) {
    __shared__ float T[64][65];
    int bid = blockIdx.x;
    int t = threadIdx.x, wave = t >> 6, lane = t & 63, lg = lane >> 4, lc = lane & 15;
    if (bid < 512) {
        int r0 = bid * 64 + wave * 16;
        const float* xrq = xq + (size_t)(r0 + lc) * 64 + lg * 8;
        const float* xrk = xk + (size_t)(r0 + lc) * 64 + lg * 8;
        bf16x8 aq[2], ak[2];
#pragma unroll
        for (int c = 0; c < 2; ++c) {
            f32x4 u0 = *(const f32x4*)(xrq + c * 32);
            f32x4 u1 = *(const f32x4*)(xrq + c * 32 + 4);
            f32x4 v0 = *(const f32x4*)(xrk + c * 32);
            f32x4 v1 = *(const f32x4*)(xrk + c * 32 + 4);
            bf16x8 a, b;
#pragma unroll
            for (int j = 0; j < 4; ++j) {
                a[j] = (__bf16)u0[j]; a[4 + j] = (__bf16)u1[j];
                b[j] = (__bf16)v0[j]; b[4 + j] = (__bf16)v1[j];
            }
            aq[c] = a; ak[c] = b;
        }
#pragma unroll
        for (int nt = 0; nt < 4; ++nt) {
            const float* wq = Wq + (size_t)(nt * 16 + lc) * 64 + lg * 8;
            const float* wk = Wk + (size_t)(nt * 16 + lc) * 64 + lg * 8;
            f32x4 cq = {0, 0, 0, 0}, ck = {0, 0, 0, 0};
#pragma unroll
            for (int c = 0; c < 2; ++c) {
                f32x4 u0 = *(const f32x4*)(wq + c * 32);
                f32x4 u1 = *(const f32x4*)(wq + c * 32 + 4);
                f32x4 v0 = *(const f32x4*)(wk + c * 32);
                f32x4 v1 = *(const f32x4*)(wk + c * 32 + 4);
                bf16x8 bw, bw2;
#pragma unroll
                for (int j = 0; j < 4; ++j) {
                    bw[j] = (__bf16)u0[j]; bw[4 + j] = (__bf16)u1[j];
                    bw2[j] = (__bf16)v0[j]; bw2[4 + j] = (__bf16)v1[j];
                }
                cq = __builtin_amdgcn_mfma_f32_16x16x32_bf16(aq[c], bw, cq, 0, 0, 0);
                ck = __builtin_amdgcn_mfma_f32_16x16x32_bf16(ak[c], bw2, ck, 0, 0, 0);
            }
            float bqv = bq[nt * 16 + lc], bkv = bk[nt * 16 + lc];
#pragma unroll
            for (int r = 0; r < 4; ++r) {
                yq[(size_t)(r0 + lg * 4 + r) * 64 + nt * 16 + lc] = (__bf16)((cq[r] + bqv) * S2EXP);
                yk[(size_t)(r0 + lg * 4 + r) * 64 + nt * 16 + lc] = (__bf16)(ck[r] + bkv);
            }
        }
    } else {
        int vb = bid - 512;
        int h = vb & 7, s0 = (vb >> 3) * 64;
        const float* xr = xv + ((size_t)(s0 + wave * 16 + lc) * 8 + h) * 64 + lg * 8;
        bf16x8 av[2];
#pragma unroll
        for (int c = 0; c < 2; ++c) {
            f32x4 u0 = *(const f32x4*)(xr + c * 32);
            f32x4 u1 = *(const f32x4*)(xr + c * 32 + 4);
            bf16x8 a;
#pragma unroll
            for (int j = 0; j < 4; ++j) { a[j] = (__bf16)u0[j]; a[4 + j] = (__bf16)u1[j]; }
            av[c] = a;
        }
#pragma unroll
        for (int nt = 0; nt < 4; ++nt) {
            const float* wv = Wv + (size_t)(nt * 16 + lc) * 64 + lg * 8;
            f32x4 cv = {0, 0, 0, 0};
#pragma unroll
            for (int c = 0; c < 2; ++c) {
                f32x4 u0 = *(const f32x4*)(wv + c * 32);
                f32x4 u1 = *(const f32x4*)(wv + c * 32 + 4);
                bf16x8 bw;
#pragma unroll
                for (int j = 0; j < 4; ++j) { bw[j] = (__bf16)u0[j]; bw[4 + j] = (__bf16)u1[j]; }
                cv = __builtin_amdgcn_mfma_f32_16x16x32_bf16(av[c], bw, cv, 0, 0, 0);
            }
            float bvv = bv[nt * 16 + lc];
#pragma unroll
            for (int r = 0; r < 4; ++r) T[wave * 16 + lg * 4 + r][nt * 16 + lc] = cv[r] + bvv;
        }
        __syncthreads();
        int d = t >> 2, qr = t & 3;
        bf16x8 w0, w1;
#pragma unroll
        for (int i = 0; i < 8; ++i) {
            w0[i] = (__bf16)T[qr * 16 + i][d];
            w1[i] = (__bf16)T[qr * 16 + 8 + i][d];
        }
        __bf16* dst = vt + ((size_t)h * 64 + d) * 4096 + s0 + qr * 16;
        *(bf16x8*)(dst) = w0;
        *(bf16x8*)(dst + 8) = w1;
    }
}

// ---------------- prep: blocks 0-2047 mask packing, 2048-2079 Wfc f32->bf16 ----------------
__global__ __launch_bounds__(256) void prep_kernel(const int* __restrict__ mask,
                                                   unsigned int* __restrict__ pack,
                                                   const float* __restrict__ Wfc,
                                                   __bf16* __restrict__ wfc_bf) {
    int bid = blockIdx.x;
    int t = threadIdx.x;
    if (bid < 2048) {
        int lane = t & 63;
        int wid = bid * 4 + (t >> 6);
#pragma unroll 4
        for (int it = 0; it < 32; ++it) {
            int gw = wid * 32 + it;
            int qi = gw >> 6, seg = gw & 63;
            unsigned long long bits = __ballot(mask[(size_t)qi * 4096 + seg * 64 + lane] != 0);
            if (lane == 0)
                *(unsigned long long*)(&pack[(size_t)qi * 128 + seg * 2]) = bits;
        }
    } else {
        int b = bid - 2048;
        const f32x4* s4 = (const f32x4*)Wfc;
#pragma unroll
        for (int i = 0; i < 8; ++i) {
            int idx = (b * 8 + i) * 256 + t;     // f32x4 index, 65536 total
            f32x4 v = s4[idx];
            bf16x4 o;
#pragma unroll
            for (int j = 0; j < 4; ++j) o[j] = (__bf16)v[j];
            *(bf16x4*)(wfc_bf + (size_t)idx * 4) = o;
        }
    }
}

// ---------------- flash attention: 32 q/wave, reg-P (K=16 PV), 4-buf vmcnt ring, setprio ----------------
// block: h = bid&7 (head -> XCD), qtb = (bid>>3)&31 (128 q-rows), sp = bid>>8
__global__ __launch_bounds__(256, 4) void attn_kernel(const __bf16* __restrict__ qb,
                                                      const __bf16* __restrict__ kb,
                                                      const __bf16* __restrict__ vt,
                                                      const unsigned int* __restrict__ mp,
                                                      int split_steps,
                                                      float* __restrict__ opart,
                                                      float* __restrict__ stats,
                                                      __bf16* __restrict__ ao) {
    int bid = blockIdx.x;
    int h = bid & 7, qtb = (bid >> 3) & 31, sp = bid >> 8;
    int kv0 = sp * split_steps * 32;
    int nsteps = min(split_steps, 128 - sp * split_steps);   // 44/44/40 — all % 4 == 0
    int t = threadIdx.x, wave = t >> 6, lane = t & 63, lg = lane >> 4, lc = lane & 15;
    int q0 = qtb * 128 + wave * 32;

    __shared__ __bf16 Kt[4][32 * 64];        // 16KB: k-rows, 128B, XOR swz ((row&7)<<4)
    __shared__ __bf16 Vt[4][64 * 32];        // 16KB: d-rows, 64B, 16B-chunk rotation swz
    __shared__ unsigned int Mld[4][128];     // 2KB: mask word per q-row per buffered tile

    int srK = lane >> 3;
    int cgK = (lane & 7) ^ srK;                      // inverse XOR swizzle (K)
    int cgV = ((lane & 3) - ((lane >> 3) & 3)) & 3;  // inverse rotation (V)
    int srV = lane >> 2;

    const __bf16* qr0 = qb + ((size_t)(q0 + lc) * 8 + h) * 64 + lg * 8;
    const __bf16* qr1 = qb + ((size_t)(q0 + 16 + lc) * 8 + h) * 64 + lg * 8;
    bf16x8 qf00 = *(const bf16x8*)(qr0);
    bf16x8 qf01 = *(const bf16x8*)(qr0 + 32);
    bf16x8 qf10 = *(const bf16x8*)(qr1);
    bf16x8 qf11 = *(const bf16x8*)(qr1 + 32);

    bf16x4 onesA;
#pragma unroll
    for (int j = 0; j < 4; ++j) onesA[j] = (__bf16)1.0f;

    f32x4 o00 = {0,0,0,0}, o01 = {0,0,0,0}, o02 = {0,0,0,0}, o03 = {0,0,0,0};
    f32x4 o10 = {0,0,0,0}, o11 = {0,0,0,0}, o12 = {0,0,0,0}, o13 = {0,0,0,0};
    f32x4 lac0 = {0,0,0,0}, lac1 = {0,0,0,0};

    const __bf16* vbase = vt + (size_t)h * 64 * 4096;
    const unsigned int* mbase = mp + (size_t)(qtb * 128 + wave * 64 + lane) * 128 + (kv0 >> 5);

    int lg4 = lg * 4;
    int vch0 = ((((lg >> 1) + (lc >> 1)) & 3) * 16) + (lg & 1) * 8;        // kc=0
    int vch1 = (((2 + (lg >> 1) + (lc >> 1)) & 3) * 16) + (lg & 1) * 8;    // kc=1

#define STAGE(tt, B)                                                                          \
    {                                                                                         \
        if (wave < 2) gload_lds4(mbase + (tt), &Mld[B][wave * 64]);                           \
        gload_lds16(kb + (size_t)(kv0 + (tt) * 32 + wave * 8 + srK) * 512 + h * 64 + cgK * 8, \
                    &Kt[B][wave * 512]);                                                      \
        gload_lds16(vbase + (size_t)(wave * 16 + srV) * 4096 + kv0 + (tt) * 32 + cgV * 8,     \
                    &Vt[B][wave * 512]);                                                      \
    }

    // ---- prologue: stage tiles 0,1; full drain once ----
    STAGE(0, 0)
    STAGE(1, 1)
    asm volatile("s_waitcnt vmcnt(0)" ::: "memory");
    __builtin_amdgcn_s_barrier();

#define ATTN_STEP(s, C, G)                                                                    \
    {                                                                                         \
        STAGE(min((s) + 2, nsteps - 1), G)                                                    \
        asm volatile("s_waitcnt vmcnt(4)" ::: "memory");                                      \
        __builtin_amdgcn_s_barrier();                                                         \
        unsigned int mw0 = Mld[C][wave * 32 + lc] >> lg4;                                     \
        unsigned int mw1 = Mld[C][wave * 32 + 16 + lc] >> lg4;                                \
        const char* Kb = (const char*)&Kt[C][0];                                              \
        f32x4 s00 = {0,0,0,0}, s01 = {0,0,0,0}, s10 = {0,0,0,0}, s11 = {0,0,0,0};             \
        {                                                                                     \
            int row = lc, sw = (row & 7) << 4;                                                \
            bf16x8 ka = *(const bf16x8*)(Kb + ((row * 128 + lg * 16) ^ sw));                  \
            bf16x8 kc_ = *(const bf16x8*)(Kb + ((row * 128 + 64 + lg * 16) ^ sw));            \
            __builtin_amdgcn_s_setprio(1);                                                    \
            s00 = __builtin_amdgcn_mfma_f32_16x16x32_bf16(ka, qf00, s00, 0, 0, 0);            \
            s00 = __builtin_amdgcn_mfma_f32_16x16x32_bf16(kc_, qf01, s00, 0, 0, 0);           \
            s01 = __builtin_amdgcn_mfma_f32_16x16x32_bf16(ka, qf10, s01, 0, 0, 0);            \
            s01 = __builtin_amdgcn_mfma_f32_16x16x32_bf16(kc_, qf11, s01, 0, 0, 0);           \
            __builtin_amdgcn_s_setprio(0);                                                    \
        }                                                                                     \
        {                                                                                     \
            int row = 16 + lc, sw = (row & 7) << 4;                                           \
            bf16x8 ka = *(const bf16x8*)(Kb + ((row * 128 + lg * 16) ^ sw));                  \
            bf16x8 kc_ = *(const bf16x8*)(Kb + ((row * 128 + 64 + lg * 16) ^ sw));            \
            __builtin_amdgcn_s_setprio(1);                                                    \
            s10 = __builtin_amdgcn_mfma_f32_16x16x32_bf16(ka, qf00, s10, 0, 0, 0);            \
            s10 = __builtin_amdgcn_mfma_f32_16x16x32_bf16(kc_, qf01, s10, 0, 0, 0);           \
            s11 = __builtin_amdgcn_mfma_f32_16x16x32_bf16(ka, qf10, s11, 0, 0, 0);            \
            s11 = __builtin_amdgcn_mfma_f32_16x16x32_bf16(kc_, qf11, s11, 0, 0, 0);           \
            __builtin_amdgcn_s_setprio(0);                                                    \
        }                                                                                     \
        bf16x4 pk00, pk10, pk01, pk11;   /* pk[kc][qt] */                                     \
        _Pragma("unroll")                                                                     \
        for (int r = 0; r < 4; ++r) {                                                         \
            float pa = __builtin_amdgcn_exp2f(s00[r]);                                        \
            pk00[r] = (__bf16)__int_as_float(__float_as_int(pa) &                             \
                                             __builtin_amdgcn_sbfe((int)mw0, r, 1));          \
            float pc = __builtin_amdgcn_exp2f(s10[r]);                                        \
            pk10[r] = (__bf16)__int_as_float(__float_as_int(pc) &                             \
                                             __builtin_amdgcn_sbfe((int)mw0, 16 + r, 1));     \
            float pd = __builtin_amdgcn_exp2f(s01[r]);                                        \
            pk01[r] = (__bf16)__int_as_float(__float_as_int(pd) &                             \
                                             __builtin_amdgcn_sbfe((int)mw1, r, 1));          \
            float pe = __builtin_amdgcn_exp2f(s11[r]);                                        \
            pk11[r] = (__bf16)__int_as_float(__float_as_int(pe) &                             \
                                             __builtin_amdgcn_sbfe((int)mw1, 16 + r, 1));     \
        }                                                                                     \
        const char* Vb = (const char*)&Vt[C][0];                                              \
        bf16x4 v00 = *(const bf16x4*)(Vb + (0 * 16 + lc) * 64 + vch0);                        \
        bf16x4 v01 = *(const bf16x4*)(Vb + (0 * 16 + lc) * 64 + vch1);                        \
        bf16x4 v10 = *(const bf16x4*)(Vb + (1 * 16 + lc) * 64 + vch0);                        \
        bf16x4 v11 = *(const bf16x4*)(Vb + (1 * 16 + lc) * 64 + vch1);                        \
        bf16x4 v20 = *(const bf16x4*)(Vb + (2 * 16 + lc) * 64 + vch0);                        \
        bf16x4 v21 = *(const bf16x4*)(Vb + (2 * 16 + lc) * 64 + vch1);                        \
        bf16x4 v30 = *(const bf16x4*)(Vb + (3 * 16 + lc) * 64 + vch0);                        \
        bf16x4 v31 = *(const bf16x4*)(Vb + (3 * 16 + lc) * 64 + vch1);                        \
        __builtin_amdgcn_s_setprio(1);                                                        \
        lac0 = mfma16(onesA, pk00, lac0);                                                     \
        lac0 = mfma16(onesA, pk10, lac0);                                                     \
        lac1 = mfma16(onesA, pk01, lac1);                                                     \
        lac1 = mfma16(onesA, pk11, lac1);                                                     \
        o00 = mfma16(v00, pk00, o00); o00 = mfma16(v01, pk10, o00);                           \
        o10 = mfma16(v00, pk01, o10); o10 = mfma16(v01, pk11, o10);                           \
        o01 = mfma16(v10, pk00, o01); o01 = mfma16(v11, pk10, o01);                           \
        o11 = mfma16(v10, pk01, o11); o11 = mfma16(v11, pk11, o11);                           \
        o02 = mfma16(v20, pk00, o02); o02 = mfma16(v21, pk10, o02);                           \
        o12 = mfma16(v20, pk01, o12); o12 = mfma16(v21, pk11, o12);                           \
        o03 = mfma16(v30, pk00, o03); o03 = mfma16(v31, pk10, o03);                           \
        o13 = mfma16(v30, pk01, o13); o13 = mfma16(v31, pk11, o13);                           \
        __builtin_amdgcn_s_setprio(0);                                                        \
    }

    for (int s = 0; s < nsteps; s += 4) {
        ATTN_STEP(s + 0, 0, 2)
        ATTN_STEP(s + 1, 1, 3)
        ATTN_STEP(s + 2, 2, 0)
        ATTN_STEP(s + 3, 3, 1)
    }
#undef ATTN_STEP
#undef STAGE

    // ---- epilogue: lane lc+16*lg holds O[q=lc(+16 for qt1)][d = dt*16 + lg*4 + r] ----
    if (opart) {
        if (lg == 0) {
            stats[(size_t)sp * 32768 + (size_t)(q0 + lc) * 8 + h]      = lac0[0];
            stats[(size_t)sp * 32768 + (size_t)(q0 + 16 + lc) * 8 + h] = lac1[0];
        }
        size_t rh0 = (size_t)sp * 32768 + (size_t)(q0 + lc) * 8 + h;
        size_t rh1 = (size_t)sp * 32768 + (size_t)(q0 + 16 + lc) * 8 + h;
        float* d0 = opart + rh0 * 64 + lg4;
        float* d1 = opart + rh1 * 64 + lg4;
        *(f32x4*)(d0 + 0)  = o00; *(f32x4*)(d0 + 16) = o01;
        *(f32x4*)(d0 + 32) = o02; *(f32x4*)(d0 + 48) = o03;
        *(f32x4*)(d1 + 0)  = o10; *(f32x4*)(d1 + 16) = o11;
        *(f32x4*)(d1 + 32) = o12; *(f32x4*)(d1 + 48) = o13;
    } else {
        float inv0 = 1.0f / lac0[0];
        float inv1 = 1.0f / lac1[0];
        __bf16* d0 = ao + (size_t)(q0 + lc) * 512 + h * 64 + lg4;
        __bf16* d1 = ao + (size_t)(q0 + 16 + lc) * 512 + h * 64 + lg4;
        bf16x4 w;
#pragma unroll
        for (int r = 0; r < 4; ++r) w[r] = (__bf16)(o00[r] * inv0);
        *(bf16x4*)(d0 + 0) = w;
#pragma unroll
        for (int r = 0; r < 4; ++r) w[r] = (__bf16)(o01[r] * inv0);
        *(bf16x4*)(d0 + 16) = w;
#pragma unroll
        for (int r = 0; r < 4; ++r) w[r] = (__bf16)(o02[r] * inv0);
        *(bf16x4*)(d0 + 32) = w;
#pragma unroll
        for (int r = 0; r < 4; ++r) w[r] = (__bf16)(o03[r] * inv0);
        *(bf16x4*)(d0 + 48) = w;
#pragma unroll
        for (int r = 0; r < 4; ++r) w[r] = (__bf16)(o10[r] * inv1);
        *(bf16x4*)(d1 + 0) = w;
#pragma unroll
        for (int r = 0; r < 4; ++r) w[r] = (__bf16)(o11[r] * inv1);
        *(bf16x4*)(d1 + 16) = w;
#pragma unroll
        for (int r = 0; r < 4; ++r) w[r] = (__bf16)(o12[r] * inv1);
        *(bf16x4*)(d1 + 32) = w;
#pragma unroll
        for (int r = 0; r < 4; ++r) w[r] = (__bf16)(o13[r] * inv1);
        *(bf16x4*)(d1 + 48) = w;
    }
}

// ---------------- split-KV combine (no-max softmax: plain sums) ----------------
__global__ __launch_bounds__(256) void combine_kernel(const float* __restrict__ opart,
                                                      const float* __restrict__ stats,
                                                      __bf16* __restrict__ ao, int nsplit) {
    int t = threadIdx.x, lane = t & 63, w = t >> 6;
    int rh = blockIdx.x * 4 + w;     // row*8 + h
    float L = 0.f, acc = 0.f;
#pragma unroll 3
    for (int sp = 0; sp < nsplit; ++sp) {
        L += stats[(size_t)sp * 32768 + rh];
        acc += opart[((size_t)sp * 32768 + rh) * 64 + lane];
    }
    int row = rh >> 3, h = rh & 7;
    ao[(size_t)row * 512 + h * 64 + lane] = (__bf16)(acc / L);
}

// ---------------- final FC: out[s][n] = sum_k ao[s][k] * Wfc[n][k] + bfc[n] ----------------
__global__ __launch_bounds__(256) void fc_kernel(const __bf16* __restrict__ ao,
                                                 const __bf16* __restrict__ Wb,
                                                 const float* __restrict__ bfc,
                                                 float* __restrict__ out) {
    int bid = blockIdx.x;
    int stile = bid >> 3, nt = bid & 7;
    int t = threadIdx.x, wave = t >> 6, lane = t & 63, lg = lane >> 4, lc = lane & 15;
    int s0 = stile * 64 + wave * 16;
    int n0 = nt * 64;
    f32x4 c0 = {0,0,0,0}, c1 = {0,0,0,0}, c2 = {0,0,0,0}, c3 = {0,0,0,0};
    for (int k0 = 0; k0 < 512; k0 += 32) {
        bf16x8 af = *(const bf16x8*)(ao + (size_t)(s0 + lc) * 512 + k0 + lg * 8);
        const __bf16* wb = Wb + k0 + lg * 8;
        c0 = __builtin_amdgcn_mfma_f32_16x16x32_bf16(af, *(const bf16x8*)(wb + (size_t)(n0 + 0 * 16 + lc) * 512), c0, 0, 0, 0);
        c1 = __builtin_amdgcn_mfma_f32_16x16x32_bf16(af, *(const bf16x8*)(wb + (size_t)(n0 + 1 * 16 + lc) * 512), c1, 0, 0, 0);
        c2 = __builtin_amdgcn_mfma_f32_16x16x32_bf16(af, *(const bf16x8*)(wb + (size_t)(n0 + 2 * 16 + lc) * 512), c2, 0, 0, 0);
        c3 = __builtin_amdgcn_mfma_f32_16x16x32_bf16(af, *(const bf16x8*)(wb + (size_t)(n0 + 3 * 16 + lc) * 512), c3, 0, 0, 0);
    }
#pragma unroll
    for (int r = 0; r < 4; ++r) {
        int row = s0 + lg * 4 + r;
        float* dst = out + (size_t)row * 512 + n0;
        dst[0 * 16 + lc] = c0[r] + bfc[n0 + 0 * 16 + lc];
        dst[1 * 16 + lc] = c1[r] + bfc[n0 + 1 * 16 + lc];
        dst[2 * 16 + lc] = c2[r] + bfc[n0 + 2 * 16 + lc];
        dst[3 * 16 + lc] = c3[r] + bfc[n0 + 3 * 16 + lc];
    }
}

extern "C" void kernel_launch(void* const* d_in, const int* in_sizes, int n_in,
                              void* d_out, int out_size, void* d_ws, size_t ws_size,
                              hipStream_t stream) {
    const float* query = (const float*)d_in[0];
    const float* key   = (const float*)d_in[1];
    const float* value = (const float*)d_in[2];
    const int*   mask  = (const int*)d_in[3];
    const float* Wq  = (const float*)d_in[4];
    const float* bq  = (const float*)d_in[5];
    const float* Wk  = (const float*)d_in[6];
    const float* bk  = (const float*)d_in[7];
    const float* Wv  = (const float*)d_in[8];
    const float* bv  = (const float*)d_in[9];
    const float* Wfc = (const float*)d_in[10];
    const float* bfc = (const float*)d_in[11];

    char* ws = (char*)d_ws;
    const size_t MB = 1024 * 1024;
    __bf16* q_bf   = (__bf16*)(ws + 0 * MB);      // 4 MB  [S*H][64]
    __bf16* k_bf   = (__bf16*)(ws + 4 * MB);      // 4 MB  [S*H][64]
    __bf16* vt     = (__bf16*)(ws + 8 * MB);      // 4 MB  [H][64][S]
    __bf16* ao     = (__bf16*)(ws + 12 * MB);     // 4 MB  [S][512]
    __bf16* wfc_bf = (__bf16*)(ws + 16 * MB);     // 0.5 MB
    unsigned int* mpack = (unsigned int*)(ws + 17 * MB);  // 2 MB [S][128]
    const size_t base = 19 * MB;
    int nsplit = (ws_size >= base + 3 * (8 * MB) + 3 * 131072) ? 3 : 1;
    float* opart = (float*)(ws + base);
    float* stats = (float*)(ws + base + (size_t)nsplit * 8 * MB);

    proj_all_kernel<<<1024, 256, 0, stream>>>(query, key, value, Wq, bq, Wk, bk, Wv, bv,
                                              q_bf, k_bf, vt);
    prep_kernel<<<2080, 256, 0, stream>>>(mask, mpack, Wfc, wfc_bf);
    if (nsplit > 1) {
        // splits of 44/44/40 steps (all % 4 == 0); grid = 32 qtb x 8 h x 3 = 768 = 3 blocks/CU
        attn_kernel<<<256 * nsplit, 256, 0, stream>>>(q_bf, k_bf, vt, mpack,
                                                      44, opart, stats, ao);
        combine_kernel<<<8192, 256, 0, stream>>>(opart, stats, ao, nsplit);
    } else {
        attn_kernel<<<256, 256, 0, stream>>>(q_bf, k_bf, vt, mpack,
                                             128, nullptr, nullptr, ao);
    }
    fc_kernel<<<512, 256, 0, stream>>>(ao, wfc_bf, bfc, (float*)d_out);
}